// Round 3
// baseline (2776.391 us; speedup 1.0000x reference)
//
#include <hip/hip_runtime.h>
#include <cstdint>
#include <cstddef>

// Problem constants: B=2, N=2048, DIM=1024, H=16, DH=64, M=16, J=M+N=2064, ROT=32
#define HS_ ((size_t)2048 * 2064)

// 16-wide mixed-head FMA: D[k] += sh * Prow[k], Prow 16B-aligned (row stride 20 floats)
#define MIX16(D, sh, Prow) do { \
    const float4 _p0 = *(const float4*)&(Prow)[0]; \
    const float4 _p1 = *(const float4*)&(Prow)[4]; \
    const float4 _p2 = *(const float4*)&(Prow)[8]; \
    const float4 _p3 = *(const float4*)&(Prow)[12]; \
    D[0]  += (sh)*_p0.x; D[1]  += (sh)*_p0.y; D[2]  += (sh)*_p0.z; D[3]  += (sh)*_p0.w; \
    D[4]  += (sh)*_p1.x; D[5]  += (sh)*_p1.y; D[6]  += (sh)*_p1.z; D[7]  += (sh)*_p1.w; \
    D[8]  += (sh)*_p2.x; D[9]  += (sh)*_p2.y; D[10] += (sh)*_p2.z; D[11] += (sh)*_p2.w; \
    D[12] += (sh)*_p3.x; D[13] += (sh)*_p3.y; D[14] += (sh)*_p3.z; D[15] += (sh)*_p3.w; \
} while (0)

// ---------------------------------------------------------------------------
// GEMM (NT): C[r][o] = sum_d A[r][d] * B[o][d] (+bias). K fixed = 1024.
// 128x128 tile, BK=16, 256 threads, 8x8 acc/thread, k-major LDS tiles
// (inner loop: 4x ds_read_b128 : 64 FMA). B selected per 128-col block.
// ---------------------------------------------------------------------------
__global__ __launch_bounds__(256) void gemm128(const float* __restrict__ A,
    const float* __restrict__ B0, const float* __restrict__ B1, const float* __restrict__ B2,
    float* __restrict__ C, const float* __restrict__ bias, int ncols)
{
    __shared__ float As[16][132];   // [k][row]
    __shared__ float Bs[16][132];
    const int tid = threadIdx.x;
    const int r0 = blockIdx.y * 128;
    const int xt = blockIdx.x;
    const float* Bm = (xt < 8) ? B0 : (xt < 16) ? B1 : B2;
    const int o_local  = (xt & 7) * 128;
    const int o_global = xt * 128;
    const int ty = tid >> 4, tx = tid & 15;
    float acc[8][8];
#pragma unroll
    for (int i = 0; i < 8; ++i)
#pragma unroll
        for (int j = 0; j < 8; ++j) acc[i][j] = 0.f;

    for (int k0 = 0; k0 < 1024; k0 += 16) {
        __syncthreads();
#pragma unroll
        for (int q = 0; q < 2; ++q) {
            const int f  = tid * 2 + q;     // 0..511
            const int rr = f >> 2;          // 0..127
            const int c4 = (f & 3) << 2;    // 0,4,8,12
            const float4 av = *(const float4*)(A  + (size_t)(r0 + rr)      * 1024 + k0 + c4);
            As[c4+0][rr] = av.x; As[c4+1][rr] = av.y; As[c4+2][rr] = av.z; As[c4+3][rr] = av.w;
            const float4 bv = *(const float4*)(Bm + (size_t)(o_local + rr) * 1024 + k0 + c4);
            Bs[c4+0][rr] = bv.x; Bs[c4+1][rr] = bv.y; Bs[c4+2][rr] = bv.z; Bs[c4+3][rr] = bv.w;
        }
        __syncthreads();
#pragma unroll
        for (int kk = 0; kk < 16; ++kk) {
            float a[8], bb[8];
            *(float4*)&a[0]  = *(const float4*)&As[kk][ty*8];
            *(float4*)&a[4]  = *(const float4*)&As[kk][ty*8+4];
            *(float4*)&bb[0] = *(const float4*)&Bs[kk][tx*8];
            *(float4*)&bb[4] = *(const float4*)&Bs[kk][tx*8+4];
#pragma unroll
            for (int i = 0; i < 8; ++i)
#pragma unroll
                for (int j = 0; j < 8; ++j) acc[i][j] += a[i] * bb[j];
        }
    }
#pragma unroll
    for (int i = 0; i < 8; ++i) {
        const int r = r0 + ty*8 + i;
        const int c = o_global + tx*8;
        float4 o0, o1;
        o0.x = acc[i][0]; o0.y = acc[i][1]; o0.z = acc[i][2]; o0.w = acc[i][3];
        o1.x = acc[i][4]; o1.y = acc[i][5]; o1.z = acc[i][6]; o1.w = acc[i][7];
        if (bias) {
            o0.x += bias[c+0]; o0.y += bias[c+1]; o0.z += bias[c+2]; o0.w += bias[c+3];
            o1.x += bias[c+4]; o1.y += bias[c+5]; o1.z += bias[c+6]; o1.w += bias[c+7];
        }
        *(float4*)(C + (size_t)r * ncols + c)     = o0;
        *(float4*)(C + (size_t)r * ncols + c + 4) = o1;
    }
}

// ---------------------------------------------------------------------------
// Rotary + scatter: qkv_raw (4096 x 3072) -> q[b,h,n,d], k/v[b,h,16+n,d]
// rotary on first 32 dims of q,k: out[d] = t[d]*cos[d] + (d<16 ? -t[d^16] : t[d^16])*sin[d]
// ---------------------------------------------------------------------------
__global__ __launch_bounds__(256) void rot_scatter(const float* __restrict__ qkv,
    const float* __restrict__ rope, float* __restrict__ q,
    float* __restrict__ kb, float* __restrict__ vb)
{
    __shared__ float cs_[32], sn_[32];
    const int r = blockIdx.x;           // 0..4095  (b*2048+n)
    const int m = blockIdx.y;           // 0:q 1:k 2:v
    const int b = r >> 11, n = r & 2047;
    if (threadIdx.x < 32) {
        const float fr = rope[n * 32 + threadIdx.x];
        cs_[threadIdx.x] = cosf(fr);
        sn_[threadIdx.x] = sinf(fr);
    }
    __syncthreads();
    const float* src = qkv + (size_t)r * 3072 + (size_t)m * 1024;
#pragma unroll
    for (int rep = 0; rep < 4; ++rep) {
        const int idx = rep * 256 + threadIdx.x;   // 0..1023
        const int h = idx >> 6, d = idx & 63;
        float val = src[idx];
        if (m < 2 && d < 32) {
            const float p = src[(h << 6) | (d ^ 16)];
            val = val * cs_[d] + ((d < 16) ? -p : p) * sn_[d];
        }
        if (m == 0)      q [((size_t)(b*16 + h) * 2048 + n)      * 64 + d] = val;
        else if (m == 1) kb[((size_t)(b*16 + h) * 2064 + 16 + n) * 64 + d] = val;
        else             vb[((size_t)(b*16 + h) * 2064 + 16 + n) * 64 + d] = val;
    }
}

// mem_k / mem_v -> first 16 slots of k/v (broadcast over b, no rotary)
__global__ __launch_bounds__(256) void memfill(const float* __restrict__ mk,
    const float* __restrict__ mv, float* __restrict__ kb, float* __restrict__ vb)
{
    const int idx = blockIdx.x * 256 + threadIdx.x;   // < 2*16*16*64 = 32768
    if (idx >= 2*16*16*64) return;
    const int d  = idx & 63;
    const int mm = (idx >> 6) & 15;
    const int h  = (idx >> 10) & 15;
    const int b  = idx >> 14;
    const size_t dst = ((size_t)(b*16 + h) * 2064 + mm) * 64 + d;
    const size_t s   = (size_t)(h*16 + mm) * 64 + d;
    kb[dst] = mk[s];
    vb[dst] = mv[s];
}

// ---------------------------------------------------------------------------
// S[b,h,i,j] = 0.125 * dot(q[b,h,i,:], k[b,h,j,:])   (writes pre_softmax_attn)
// 64x64 tile per block, K=64 single pass, k-major LDS tiles.
// ---------------------------------------------------------------------------
__global__ __launch_bounds__(256) void qk_kernel(const float* __restrict__ q,
    const float* __restrict__ kb, float* __restrict__ S)
{
    __shared__ float Qs[64][68];   // [k][i-row]
    __shared__ float Ks[64][68];   // [k][j-row]
    const int tid = threadIdx.x;
    const int j0 = blockIdx.x * 64, i0 = blockIdx.y * 64, bh = blockIdx.z;
    const int rr = tid >> 2, qq = tid & 3;
    {
        const float4* qs = (const float4*)(q + ((size_t)bh * 2048 + i0 + rr) * 64 + qq * 16);
#pragma unroll
        for (int e = 0; e < 4; ++e) {
            const float4 t = qs[e]; const int c = qq*16 + e*4;
            Qs[c+0][rr] = t.x; Qs[c+1][rr] = t.y; Qs[c+2][rr] = t.z; Qs[c+3][rr] = t.w;
        }
        const int jrow = j0 + rr;
        if (jrow < 2064) {
            const float4* ks = (const float4*)(kb + ((size_t)bh * 2064 + jrow) * 64 + qq * 16);
#pragma unroll
            for (int e = 0; e < 4; ++e) {
                const float4 t = ks[e]; const int c = qq*16 + e*4;
                Ks[c+0][rr] = t.x; Ks[c+1][rr] = t.y; Ks[c+2][rr] = t.z; Ks[c+3][rr] = t.w;
            }
        } else {
#pragma unroll
            for (int e = 0; e < 16; ++e) Ks[qq*16 + e][rr] = 0.f;
        }
    }
    __syncthreads();
    const int ty = tid >> 4, tx = tid & 15;
    float acc[4][4];
#pragma unroll
    for (int i = 0; i < 4; ++i)
#pragma unroll
        for (int j = 0; j < 4; ++j) acc[i][j] = 0.f;
#pragma unroll
    for (int kk = 0; kk < 64; ++kk) {
        const float4 a4 = *(const float4*)&Qs[kk][ty * 4];
        const float4 b4 = *(const float4*)&Ks[kk][tx * 4];
        acc[0][0] += a4.x*b4.x; acc[0][1] += a4.x*b4.y; acc[0][2] += a4.x*b4.z; acc[0][3] += a4.x*b4.w;
        acc[1][0] += a4.y*b4.x; acc[1][1] += a4.y*b4.y; acc[1][2] += a4.y*b4.z; acc[1][3] += a4.y*b4.w;
        acc[2][0] += a4.z*b4.x; acc[2][1] += a4.z*b4.y; acc[2][2] += a4.z*b4.z; acc[2][3] += a4.z*b4.w;
        acc[3][0] += a4.w*b4.x; acc[3][1] += a4.w*b4.y; acc[3][2] += a4.w*b4.z; acc[3][3] += a4.w*b4.w;
    }
    const int jcol = j0 + tx*4;
    if (jcol < 2064) {
#pragma unroll
        for (int i = 0; i < 4; ++i) {
            float4 o4;
            o4.x = acc[i][0]*0.125f; o4.y = acc[i][1]*0.125f;
            o4.z = acc[i][2]*0.125f; o4.w = acc[i][3]*0.125f;
            *(float4*)(S + ((size_t)bh * 2048 + i0 + ty*4 + i) * 2064 + jcol) = o4;
        }
    }
}

// ---------------------------------------------------------------------------
// Softmax stats: for each (b,i), mixed logits D[k,j] = sum_h S[h,j]*pre_proj[h,k],
// causal-masked (keep j <= i+16); outputs max m[b,k,i] and 1/sum linv[b,k,i].
// ---------------------------------------------------------------------------
__global__ __launch_bounds__(256) void stats_kernel(const float* __restrict__ S,
    const float* __restrict__ prew, float* __restrict__ mOut, float* __restrict__ lOut)
{
    __shared__ float P[16][20];
    __shared__ float red[4][16][2];
    const int tid = threadIdx.x;
    P[tid >> 4][tid & 15] = prew[tid];
    __syncthreads();
    const int bi = blockIdx.x;
    const int b = bi >> 11, i = bi & 2047;
    const float* Sb_ = S + (size_t)b * 16 * HS_ + (size_t)i * 2064;
    float m[16], l[16];
#pragma unroll
    for (int k = 0; k < 16; ++k) { m[k] = -3.0e38f; l[k] = 0.f; }
    const int jmax = i + 16;   // inclusive last valid j
    for (int jj = tid; jj <= jmax; jj += 256) {
        float D[16];
#pragma unroll
        for (int k = 0; k < 16; ++k) D[k] = 0.f;
#pragma unroll
        for (int h = 0; h < 16; ++h) {
            const float sh = Sb_[(size_t)h * HS_ + jj];
            MIX16(D, sh, P[h]);
        }
#pragma unroll
        for (int k = 0; k < 16; ++k) {
            const float dv = D[k];
            const float M  = fmaxf(m[k], dv);
            l[k] = l[k] * __expf(m[k] - M) + __expf(dv - M);
            m[k] = M;
        }
    }
    // 64-lane butterfly merge of (m,l) per k (branch-free; exp(-huge)=0)
#pragma unroll
    for (int off = 1; off < 64; off <<= 1) {
#pragma unroll
        for (int k = 0; k < 16; ++k) {
            const float mo = __shfl_xor(m[k], off);
            const float lo = __shfl_xor(l[k], off);
            const float M  = fmaxf(m[k], mo);
            l[k] = l[k] * __expf(m[k] - M) + lo * __expf(mo - M);
            m[k] = M;
        }
    }
    const int wv = tid >> 6, lane = tid & 63;
    if (lane == 0) {
#pragma unroll
        for (int k = 0; k < 16; ++k) { red[wv][k][0] = m[k]; red[wv][k][1] = l[k]; }
    }
    __syncthreads();
    if (tid < 16) {
        float M = red[0][tid][0], L = red[0][tid][1];
#pragma unroll
        for (int w = 1; w < 4; ++w) {
            const float mo = red[w][tid][0], lo = red[w][tid][1];
            const float Mn = fmaxf(M, mo);
            L = L * __expf(M - Mn) + lo * __expf(mo - Mn);
            M = Mn;
        }
        mOut[((size_t)b*16 + tid) * 2048 + i] = M;
        lOut[((size_t)b*16 + tid) * 2048 + i] = 1.0f / L;
    }
}

// ---------------------------------------------------------------------------
// Zero-fill the causally-masked part of post_softmax_attn (j > i+16), coalesced.
// One block per (b,k,i) row.
// ---------------------------------------------------------------------------
__global__ __launch_bounds__(256) void zerofill(float* __restrict__ post)
{
    const int row = blockIdx.x;           // ((b*16+k)*2048 + i)
    const int i = row & 2047;
    float* p = post + (size_t)row * 2064;
    for (int j = i + 17 + threadIdx.x; j < 2064; j += 256) p[j] = 0.f;
}

// ---------------------------------------------------------------------------
// Fused: D=pre-mix -> A=softmax (write post) -> A2=post-mix -> PV accumulate.
// No S/V LDS staging (zero intra-block reuse); only A2t transpose buffer in LDS.
// Mix role: thread=(il,jl). PV role: thread=(head kh, d-quad dq).
// Visits only causal-band tiles t in [jc, it+1] step 4. atomicAdd into ho.
// ---------------------------------------------------------------------------
__global__ __launch_bounds__(256) void fused_kernel(const float* __restrict__ S,
    float* __restrict__ Apost, const float* __restrict__ vb,
    const float* __restrict__ prew, const float* __restrict__ postw,
    const float* __restrict__ mIn, const float* __restrict__ lIn,
    float* __restrict__ ho)
{
    __shared__ float A2t[5184];          // addr = k*324 + jl*20 + il  (bank-staggered)
    __shared__ float Pp[16][20], Po[16][20];
    __shared__ float Ms[16][16], Ls[16][16];   // [k][il]
    const int tid = threadIdx.x;
    const int it = blockIdx.x, jc = blockIdx.y, b = blockIdx.z;
    const int i0 = it * 16;
    const int tmax = it + 1;             // last causal tile (tile it+2 is fully masked)
    if (jc > tmax) return;               // uniform over block
    {
        const int h = tid >> 4, c = tid & 15;
        Pp[h][c] = prew[tid];
        Po[h][c] = postw[tid];
        Ms[h][c] = mIn[((size_t)b*16 + h) * 2048 + i0 + c];
        Ls[h][c] = lIn[((size_t)b*16 + h) * 2048 + i0 + c];
    }
    __syncthreads();
    const int il = tid >> 4, jl = tid & 15;
    float msr[16], lsr[16];
#pragma unroll
    for (int k = 0; k < 16; ++k) { msr[k] = Ms[k][il]; lsr[k] = Ls[k][il]; }
    const int ig = i0 + il;
    const float* Sbase = S     + (size_t)b*16*HS_ + (size_t)ig * 2064 + jl;   // +h*HS_+j0
    float*       Pbase = Apost + (size_t)b*16*HS_ + (size_t)ig * 2064 + jl;   // +k*HS_+j0
    const int kh = il, dq = jl;          // PV-role decomposition of the same tid
    const float* Vbase = vb + ((size_t)(b*16 + kh) * 2064) * 64 + dq * 4;     // +(j0+j)*64
    float* a2w       = &A2t[jl*20 + il]; // + k*324
    const float* a2r = &A2t[kh*324];     // + j*20 + q*4
    float acc[16][4];
#pragma unroll
    for (int i = 0; i < 16; ++i)
#pragma unroll
        for (int e = 0; e < 4; ++e) acc[i][e] = 0.f;

    for (int t = jc; t <= tmax; t += 4) {
        const int j0 = t * 16;
        const int jg = j0 + jl;
        // ---- pre-mix: D[k] = sum_h S[h,ig,jg] * pre_proj[h][k] ----
        float D[16];
#pragma unroll
        for (int k = 0; k < 16; ++k) D[k] = 0.f;
#pragma unroll
        for (int h = 0; h < 16; ++h) {
            const float sh = Sbase[(size_t)h * HS_ + j0];
            MIX16(D, sh, Pp[h]);
        }
        // ---- softmax + write post ----
        const bool masked = jg > ig + 16;
        float A[16];
#pragma unroll
        for (int k = 0; k < 16; ++k)
            A[k] = masked ? 0.f : __expf(D[k] - msr[k]) * lsr[k];
#pragma unroll
        for (int k = 0; k < 16; ++k)
            Pbase[(size_t)k * HS_ + j0] = A[k];
        // ---- post-mix: A2[k] = sum_h A[h] * post_proj[h][k] ----
        float A2[16];
#pragma unroll
        for (int k = 0; k < 16; ++k) A2[k] = 0.f;
#pragma unroll
        for (int h = 0; h < 16; ++h) {
            const float ah = A[h];
            MIX16(A2, ah, Po[h]);
        }
#pragma unroll
        for (int k = 0; k < 16; ++k) a2w[k * 324] = A2[k];
        __syncthreads();   // A2t visible
        // ---- PV: acc[i][e] += A2[kh, i0+i, j0+j] * v[b,kh, j0+j, dq*4+e] ----
#pragma unroll
        for (int j = 0; j < 16; ++j) {
            const float4 v4 = *(const float4*)(Vbase + (size_t)(j0 + j) * 64);
            const float* ap = a2r + j * 20;
#pragma unroll
            for (int qq = 0; qq < 4; ++qq) {
                const float4 a4 = *(const float4*)(ap + qq * 4);
                acc[qq*4+0][0] += a4.x*v4.x; acc[qq*4+0][1] += a4.x*v4.y;
                acc[qq*4+0][2] += a4.x*v4.z; acc[qq*4+0][3] += a4.x*v4.w;
                acc[qq*4+1][0] += a4.y*v4.x; acc[qq*4+1][1] += a4.y*v4.y;
                acc[qq*4+1][2] += a4.y*v4.z; acc[qq*4+1][3] += a4.y*v4.w;
                acc[qq*4+2][0] += a4.z*v4.x; acc[qq*4+2][1] += a4.z*v4.y;
                acc[qq*4+2][2] += a4.z*v4.z; acc[qq*4+2][3] += a4.z*v4.w;
                acc[qq*4+3][0] += a4.w*v4.x; acc[qq*4+3][1] += a4.w*v4.y;
                acc[qq*4+3][2] += a4.w*v4.z; acc[qq*4+3][3] += a4.w*v4.w;
            }
        }
        __syncthreads();   // PV reads done before next tile's A2t writes
    }
#pragma unroll
    for (int i = 0; i < 16; ++i) {
        float* dst = ho + ((size_t)(b*2048 + i0 + i)) * 1024 + kh*64 + dq*4;
        atomicAdd(dst+0, acc[i][0]);
        atomicAdd(dst+1, acc[i][1]);
        atomicAdd(dst+2, acc[i][2]);
        atomicAdd(dst+3, acc[i][3]);
    }
}

// ---------------------------------------------------------------------------
extern "C" void kernel_launch(void* const* d_in, const int* in_sizes, int n_in,
                              void* d_out, int out_size, void* d_ws, size_t ws_size,
                              hipStream_t stream)
{
    const float* x     = (const float*)d_in[0];
    const float* rope  = (const float*)d_in[1];
    const float* Wq    = (const float*)d_in[2];
    const float* Wk    = (const float*)d_in[3];
    const float* Wv    = (const float*)d_in[4];
    const float* memk  = (const float*)d_in[5];
    const float* memv  = (const float*)d_in[6];
    const float* prew  = (const float*)d_in[7];
    const float* postw = (const float*)d_in[8];
    const float* Wo    = (const float*)d_in[9];
    const float* bo    = (const float*)d_in[10];

    float* out  = (float*)d_out;                      // (2,2048,1024)
    float* pre  = out + (size_t)4194304;              // (2,16,2048,2064)
    float* post = pre + (size_t)135266304;            // (2,16,2048,2064)

    // Scratch parked in the `post` output region (dead before zerofill/fused):
    float* qkv_raw = post;                 // 4096 x 3072        (12,582,912)
    float* qbuf    = post + 12582912;      // (2,16,2048,64)     ( 4,194,304)
    float* kbuf    = post + 16777216;      // (2,16,2064,64)     ( 4,227,072)

    // Persistent scratch in d_ws (needs 34.2 MB):
    float* vbuf = (float*)d_ws;            // (2,16,2064,64)     ( 4,227,072)
    float* ho   = vbuf + 4227072;          // (2,2048,1024)      ( 4,194,304)
    float* mst  = ho + 4194304;            // (2,16,2048)        (    65,536)
    float* linv = mst + 65536;             // (2,16,2048)        (    65,536)
    if (ws_size < (size_t)8552448 * 4) return;

    // 1) QKV projection: (4096x1024) @ (1024x3072)
    gemm128<<<dim3(24, 32), 256, 0, stream>>>(x, Wq, Wk, Wv, qkv_raw, nullptr, 3072);
    // 2) rotary + scatter to q/k/v layouts
    rot_scatter<<<dim3(4096, 3), 256, 0, stream>>>(qkv_raw, rope, qbuf, kbuf, vbuf);
    // 3) prepend memory k/v
    memfill<<<dim3(128), 256, 0, stream>>>(memk, memv, kbuf, vbuf);
    // 4) S = scale * q k^T  -> pre_softmax_attn (full, unmasked)
    qk_kernel<<<dim3(33, 32, 32), 256, 0, stream>>>(qbuf, kbuf, pre);
    // 5) softmax stats of head-mixed masked logits
    stats_kernel<<<dim3(4096), 256, 0, stream>>>(pre, prew, mst, linv);
    // 6a) zero the masked part of post (overwrites qkv_raw/qbuf/kbuf - now dead)
    zerofill<<<dim3(65536), 256, 0, stream>>>(post);
    // 6b) ho = 0, then fused softmax-write + post-mix + PV (causal band only)
    hipMemsetAsync(ho, 0, (size_t)4194304 * 4, stream);
    fused_kernel<<<dim3(128, 4, 2), 256, 0, stream>>>(pre, post, vbuf, prew, postw, mst, linv, ho);
    // 7) out = ho @ Wo^T + bo
    gemm128<<<dim3(8, 32), 256, 0, stream>>>(ho, Wo, Wo, Wo, out, bo, 1024);
}

// Round 4
// 2537.447 us; speedup vs baseline: 1.0942x; 1.0942x over previous
//
#include <hip/hip_runtime.h>
#include <cstdint>
#include <cstddef>

// Problem constants: B=2, N=2048, DIM=1024, H=16, DH=64, M=16, J=M+N=2064, ROT=32
#define HS_ ((size_t)2048 * 2064)

// 16-wide mixed-head FMA: D[k] += sh * Prow[k], Prow 16B-aligned (row stride 20 floats)
#define MIX16(D, sh, Prow) do { \
    const float4 _p0 = *(const float4*)&(Prow)[0]; \
    const float4 _p1 = *(const float4*)&(Prow)[4]; \
    const float4 _p2 = *(const float4*)&(Prow)[8]; \
    const float4 _p3 = *(const float4*)&(Prow)[12]; \
    D[0]  += (sh)*_p0.x; D[1]  += (sh)*_p0.y; D[2]  += (sh)*_p0.z; D[3]  += (sh)*_p0.w; \
    D[4]  += (sh)*_p1.x; D[5]  += (sh)*_p1.y; D[6]  += (sh)*_p1.z; D[7]  += (sh)*_p1.w; \
    D[8]  += (sh)*_p2.x; D[9]  += (sh)*_p2.y; D[10] += (sh)*_p2.z; D[11] += (sh)*_p2.w; \
    D[12] += (sh)*_p3.x; D[13] += (sh)*_p3.y; D[14] += (sh)*_p3.z; D[15] += (sh)*_p3.w; \
} while (0)

// ---------------------------------------------------------------------------
// GEMM (NT): C[r][o] = sum_d A[r][d] * B[o][d] (+bias). K fixed = 1024.
// 128x128 tile, BK=16, 256 threads, 8x8 acc/thread, k-major LDS tiles.
// ---------------------------------------------------------------------------
__global__ __launch_bounds__(256) void gemm128(const float* __restrict__ A,
    const float* __restrict__ B0, const float* __restrict__ B1, const float* __restrict__ B2,
    float* __restrict__ C, const float* __restrict__ bias, int ncols)
{
    __shared__ float As[16][132];   // [k][row]
    __shared__ float Bs[16][132];
    const int tid = threadIdx.x;
    const int r0 = blockIdx.y * 128;
    const int xt = blockIdx.x;
    const float* Bm = (xt < 8) ? B0 : (xt < 16) ? B1 : B2;
    const int o_local  = (xt & 7) * 128;
    const int o_global = xt * 128;
    const int ty = tid >> 4, tx = tid & 15;
    float acc[8][8];
#pragma unroll
    for (int i = 0; i < 8; ++i)
#pragma unroll
        for (int j = 0; j < 8; ++j) acc[i][j] = 0.f;

    for (int k0 = 0; k0 < 1024; k0 += 16) {
        __syncthreads();
#pragma unroll
        for (int q = 0; q < 2; ++q) {
            const int f  = tid * 2 + q;     // 0..511
            const int rr = f >> 2;          // 0..127
            const int c4 = (f & 3) << 2;    // 0,4,8,12
            const float4 av = *(const float4*)(A  + (size_t)(r0 + rr)      * 1024 + k0 + c4);
            As[c4+0][rr] = av.x; As[c4+1][rr] = av.y; As[c4+2][rr] = av.z; As[c4+3][rr] = av.w;
            const float4 bv = *(const float4*)(Bm + (size_t)(o_local + rr) * 1024 + k0 + c4);
            Bs[c4+0][rr] = bv.x; Bs[c4+1][rr] = bv.y; Bs[c4+2][rr] = bv.z; Bs[c4+3][rr] = bv.w;
        }
        __syncthreads();
#pragma unroll
        for (int kk = 0; kk < 16; ++kk) {
            float a[8], bb[8];
            *(float4*)&a[0]  = *(const float4*)&As[kk][ty*8];
            *(float4*)&a[4]  = *(const float4*)&As[kk][ty*8+4];
            *(float4*)&bb[0] = *(const float4*)&Bs[kk][tx*8];
            *(float4*)&bb[4] = *(const float4*)&Bs[kk][tx*8+4];
#pragma unroll
            for (int i = 0; i < 8; ++i)
#pragma unroll
                for (int j = 0; j < 8; ++j) acc[i][j] += a[i] * bb[j];
        }
    }
#pragma unroll
    for (int i = 0; i < 8; ++i) {
        const int r = r0 + ty*8 + i;
        const int c = o_global + tx*8;
        float4 o0, o1;
        o0.x = acc[i][0]; o0.y = acc[i][1]; o0.z = acc[i][2]; o0.w = acc[i][3];
        o1.x = acc[i][4]; o1.y = acc[i][5]; o1.z = acc[i][6]; o1.w = acc[i][7];
        if (bias) {
            o0.x += bias[c+0]; o0.y += bias[c+1]; o0.z += bias[c+2]; o0.w += bias[c+3];
            o1.x += bias[c+4]; o1.y += bias[c+5]; o1.z += bias[c+6]; o1.w += bias[c+7];
        }
        *(float4*)(C + (size_t)r * ncols + c)     = o0;
        *(float4*)(C + (size_t)r * ncols + c + 4) = o1;
    }
}

// ---------------------------------------------------------------------------
// Rotary + scatter: qkv_raw (4096 x 3072) -> q[b,h,n,d], k/v[b,h,16+n,d]
// ---------------------------------------------------------------------------
__global__ __launch_bounds__(256) void rot_scatter(const float* __restrict__ qkv,
    const float* __restrict__ rope, float* __restrict__ q,
    float* __restrict__ kb, float* __restrict__ vb)
{
    __shared__ float cs_[32], sn_[32];
    const int r = blockIdx.x;           // 0..4095  (b*2048+n)
    const int m = blockIdx.y;           // 0:q 1:k 2:v
    const int b = r >> 11, n = r & 2047;
    if (threadIdx.x < 32) {
        const float fr = rope[n * 32 + threadIdx.x];
        cs_[threadIdx.x] = cosf(fr);
        sn_[threadIdx.x] = sinf(fr);
    }
    __syncthreads();
    const float* src = qkv + (size_t)r * 3072 + (size_t)m * 1024;
#pragma unroll
    for (int rep = 0; rep < 4; ++rep) {
        const int idx = rep * 256 + threadIdx.x;   // 0..1023
        const int h = idx >> 6, d = idx & 63;
        float val = src[idx];
        if (m < 2 && d < 32) {
            const float p = src[(h << 6) | (d ^ 16)];
            val = val * cs_[d] + ((d < 16) ? -p : p) * sn_[d];
        }
        if (m == 0)      q [((size_t)(b*16 + h) * 2048 + n)      * 64 + d] = val;
        else if (m == 1) kb[((size_t)(b*16 + h) * 2064 + 16 + n) * 64 + d] = val;
        else             vb[((size_t)(b*16 + h) * 2064 + 16 + n) * 64 + d] = val;
    }
}

// mem_k / mem_v -> first 16 slots of k/v (broadcast over b, no rotary)
__global__ __launch_bounds__(256) void memfill(const float* __restrict__ mk,
    const float* __restrict__ mv, float* __restrict__ kb, float* __restrict__ vb)
{
    const int idx = blockIdx.x * 256 + threadIdx.x;   // < 2*16*16*64 = 32768
    if (idx >= 2*16*16*64) return;
    const int d  = idx & 63;
    const int mm = (idx >> 6) & 15;
    const int h  = (idx >> 10) & 15;
    const int b  = idx >> 14;
    const size_t dst = ((size_t)(b*16 + h) * 2064 + mm) * 64 + d;
    const size_t s   = (size_t)(h*16 + mm) * 64 + d;
    kb[dst] = mk[s];
    vb[dst] = mv[s];
}

// ---------------------------------------------------------------------------
// S[b,h,i,j] = 0.125 * dot(q[b,h,i,:], k[b,h,j,:])  (writes pre_softmax_attn)
// 128(i) x 64(j) tile per block, K=64 single pass, k-major LDS,
// 8x4 acc/thread -> 32 FMA per 3 ds_read_b128.
// ---------------------------------------------------------------------------
__global__ __launch_bounds__(256) void qk_kernel(const float* __restrict__ q,
    const float* __restrict__ kb, float* __restrict__ S)
{
    __shared__ float Qs[64][132];   // [k][i-row 0..127]
    __shared__ float Ks[64][68];    // [k][j-row 0..63]
    const int tid = threadIdx.x;
    const int j0 = blockIdx.x * 64, i0 = blockIdx.y * 128, bh = blockIdx.z;
    {
        const float* Qg = q + ((size_t)bh * 2048 + i0) * 64;
#pragma unroll
        for (int e = 0; e < 8; ++e) {
            const int idx = e * 256 + tid;      // 0..2047 float4 units
            const int row = idx >> 4;           // 0..127
            const int c4  = (idx & 15) << 2;    // 0..60
            const float4 t = *(const float4*)(Qg + (size_t)row * 64 + c4);
            Qs[c4+0][row] = t.x; Qs[c4+1][row] = t.y; Qs[c4+2][row] = t.z; Qs[c4+3][row] = t.w;
        }
        const float* Kg = kb + ((size_t)bh * 2064) * 64;
#pragma unroll
        for (int e = 0; e < 4; ++e) {
            const int idx = e * 256 + tid;      // 0..1023
            const int row = idx >> 4;           // 0..63
            const int c4  = (idx & 15) << 2;
            const int jrow = j0 + row;
            if (jrow < 2064) {
                const float4 t = *(const float4*)(Kg + (size_t)jrow * 64 + c4);
                Ks[c4+0][row] = t.x; Ks[c4+1][row] = t.y; Ks[c4+2][row] = t.z; Ks[c4+3][row] = t.w;
            } else {
                Ks[c4+0][row] = 0.f; Ks[c4+1][row] = 0.f; Ks[c4+2][row] = 0.f; Ks[c4+3][row] = 0.f;
            }
        }
    }
    __syncthreads();
    const int ty = tid >> 4, tx = tid & 15;
    float acc[8][4];
#pragma unroll
    for (int i = 0; i < 8; ++i)
#pragma unroll
        for (int j = 0; j < 4; ++j) acc[i][j] = 0.f;
#pragma unroll
    for (int kk = 0; kk < 64; ++kk) {
        float a[8];
        *(float4*)&a[0] = *(const float4*)&Qs[kk][ty*8];
        *(float4*)&a[4] = *(const float4*)&Qs[kk][ty*8+4];
        const float4 b4 = *(const float4*)&Ks[kk][tx*4];
#pragma unroll
        for (int i = 0; i < 8; ++i) {
            acc[i][0] += a[i]*b4.x; acc[i][1] += a[i]*b4.y;
            acc[i][2] += a[i]*b4.z; acc[i][3] += a[i]*b4.w;
        }
    }
    const int jcol = j0 + tx*4;
    if (jcol < 2064) {
#pragma unroll
        for (int i = 0; i < 8; ++i) {
            float4 o4;
            o4.x = acc[i][0]*0.125f; o4.y = acc[i][1]*0.125f;
            o4.z = acc[i][2]*0.125f; o4.w = acc[i][3]*0.125f;
            *(float4*)(S + ((size_t)bh * 2048 + i0 + ty*8 + i) * 2064 + jcol) = o4;
        }
    }
}

// ---------------------------------------------------------------------------
// Softmax stats: for each (b,i), mixed logits D[k,j] = sum_h S[h,j]*pre_proj[h,k],
// causal (keep j <= i+16); outputs max m[b,k,i] and 1/sum linv[b,k,i].
// ---------------------------------------------------------------------------
__global__ __launch_bounds__(256) void stats_kernel(const float* __restrict__ S,
    const float* __restrict__ prew, float* __restrict__ mOut, float* __restrict__ lOut)
{
    __shared__ float P[16][20];
    __shared__ float red[4][16][2];
    const int tid = threadIdx.x;
    P[tid >> 4][tid & 15] = prew[tid];
    __syncthreads();
    const int bi = blockIdx.x;
    const int b = bi >> 11, i = bi & 2047;
    const float* Sb_ = S + (size_t)b * 16 * HS_ + (size_t)i * 2064;
    float m[16], l[16];
#pragma unroll
    for (int k = 0; k < 16; ++k) { m[k] = -3.0e38f; l[k] = 0.f; }
    const int jmax = i + 16;   // inclusive last valid j
    for (int jj = tid; jj <= jmax; jj += 256) {
        float D[16];
#pragma unroll
        for (int k = 0; k < 16; ++k) D[k] = 0.f;
#pragma unroll
        for (int h = 0; h < 16; ++h) {
            const float sh = Sb_[(size_t)h * HS_ + jj];
            MIX16(D, sh, P[h]);
        }
#pragma unroll
        for (int k = 0; k < 16; ++k) {
            const float dv = D[k];
            const float M  = fmaxf(m[k], dv);
            l[k] = l[k] * __expf(m[k] - M) + __expf(dv - M);
            m[k] = M;
        }
    }
#pragma unroll
    for (int off = 1; off < 64; off <<= 1) {
#pragma unroll
        for (int k = 0; k < 16; ++k) {
            const float mo = __shfl_xor(m[k], off);
            const float lo = __shfl_xor(l[k], off);
            const float M  = fmaxf(m[k], mo);
            l[k] = l[k] * __expf(m[k] - M) + lo * __expf(mo - M);
            m[k] = M;
        }
    }
    const int wv = tid >> 6, lane = tid & 63;
    if (lane == 0) {
#pragma unroll
        for (int k = 0; k < 16; ++k) { red[wv][k][0] = m[k]; red[wv][k][1] = l[k]; }
    }
    __syncthreads();
    if (tid < 16) {
        float M = red[0][tid][0], L = red[0][tid][1];
#pragma unroll
        for (int w = 1; w < 4; ++w) {
            const float mo = red[w][tid][0], lo = red[w][tid][1];
            const float Mn = fmaxf(M, mo);
            L = L * __expf(M - Mn) + lo * __expf(mo - Mn);
            M = Mn;
        }
        mOut[((size_t)b*16 + tid) * 2048 + i] = M;
        lOut[((size_t)b*16 + tid) * 2048 + i] = 1.0f / L;
    }
}

// ---------------------------------------------------------------------------
// Zero-fill the causally-masked part of post_softmax_attn (j > i+16).
// ---------------------------------------------------------------------------
__global__ __launch_bounds__(256) void zerofill(float* __restrict__ post)
{
    const int row = blockIdx.x;           // ((b*16+k)*2048 + i)
    const int i = row & 2047;
    float* p = post + (size_t)row * 2064;
    for (int j = i + 17 + threadIdx.x; j < 2064; j += 256) p[j] = 0.f;
}

// ---------------------------------------------------------------------------
// Fused: D=pre-mix -> A=softmax (write post) -> A2=post-mix -> PV accumulate.
// 512 threads. Balanced it-pairing: block (itp,jc,b) handles i-tiles itp and
// 127-itp; each processes its causal band's 32-j units u = jc, jc+4, ...
// Grid (64,4,2) = 512 blocks x 8 waves = exactly full MI355X residency.
// Mix role: thread=(il=tid>>5, jl=tid&31). PV role: (kh=tid>>5, ih, dq).
// A2t layout [k][i][j] word = k*544 + i*34 + j (pad 34: 2-way banks, b64 ok).
// ---------------------------------------------------------------------------
#define JP 34
#define KP 544   // 16*34
__global__ __launch_bounds__(512) void fused_kernel(const float* __restrict__ S,
    float* __restrict__ Apost, const float* __restrict__ vb,
    const float* __restrict__ prew, const float* __restrict__ postw,
    const float* __restrict__ mIn, const float* __restrict__ lIn,
    float* __restrict__ ho)
{
    __shared__ float A2t[16 * KP / 16 * 16];   // 16*544 = 8704 words = 34.8 KB
    __shared__ float Pp[16][20], Po[16][20];
    __shared__ float Ms[16][16], Ls[16][16];
    const int tid = threadIdx.x;
    const int itp = blockIdx.x, jc = blockIdx.y, b = blockIdx.z;
    if (tid < 256) {
        Pp[tid >> 4][tid & 15] = prew[tid];
        Po[tid >> 4][tid & 15] = postw[tid];
    }
    const int il = tid >> 5, jl = tid & 31;      // mix role
    const int kh = tid >> 5;                     // PV role
    const int ih = (tid >> 4) & 1, dq = tid & 15;
    const float* Vb0 = vb + ((size_t)(b*16 + kh) * 2064) * 64 + dq * 4;

#pragma unroll 1
    for (int seg = 0; seg < 2; ++seg) {
        const int it = seg ? (127 - itp) : itp;
        const int i0 = it * 16;
        const int ig = i0 + il;
        // stats for this i-tile
        if (tid < 256) {
            const int h = tid >> 4, c = tid & 15;
            Ms[h][c] = mIn[((size_t)b*16 + h) * 2048 + i0 + c];
            Ls[h][c] = lIn[((size_t)b*16 + h) * 2048 + i0 + c];
        }
        __syncthreads();
        const float* Sb = S     + (size_t)b*16*HS_ + (size_t)ig * 2064;
        float*       Pb = Apost + (size_t)b*16*HS_ + (size_t)ig * 2064;
        float acc[8][4];
#pragma unroll
        for (int r = 0; r < 8; ++r)
#pragma unroll
            for (int e = 0; e < 4; ++e) acc[r][e] = 0.f;

        const int U = (it + 3) >> 1;             // ceil((it+2)/2) 32-j units
#pragma unroll 1
        for (int u = jc; u < U; u += 4) {
            const int j0 = u * 32;
            const int jg = j0 + jl;
            const int sjg = (jg < 2064) ? jg : 2063;
            // ---- load S (coalesced: 2 rows x 128B per wave per h) ----
            float s[16];
#pragma unroll
            for (int h = 0; h < 16; ++h) s[h] = Sb[(size_t)h * HS_ + sjg];
            // ---- pre-mix ----
            float D[16];
#pragma unroll
            for (int k = 0; k < 16; ++k) D[k] = 0.f;
#pragma unroll
            for (int h = 0; h < 16; ++h) MIX16(D, s[h], Pp[h]);
            // ---- softmax (mask covers jg>=2064 too since ig+16<=2063) ----
            const bool live = (jg <= ig + 16);
            float A[16];
#pragma unroll
            for (int k = 0; k < 16; ++k) {
                const float e = __expf(D[k] - Ms[k][il]) * Ls[k][il];
                A[k] = live ? e : 0.f;
            }
            // ---- write post (band region) ----
            if (jg < 2064) {
#pragma unroll
                for (int k = 0; k < 16; ++k) Pb[(size_t)k * HS_ + jg] = A[k];
            }
            // ---- post-mix ----
            float A2[16];
#pragma unroll
            for (int k = 0; k < 16; ++k) A2[k] = 0.f;
#pragma unroll
            for (int h = 0; h < 16; ++h) MIX16(A2, A[h], Po[h]);
            // ---- transpose via LDS ----
            float* w = &A2t[il * JP + jl];
#pragma unroll
            for (int k = 0; k < 16; ++k) w[k * KP] = A2[k];
            __syncthreads();
            // ---- PV: thread (kh, ih, dq), 8 i-rows x 4 d ----
            const float* ar = &A2t[kh * KP + (ih * 8) * JP];
#pragma unroll
            for (int j = 0; j < 32; j += 2) {
                int ja0 = j0 + j, ja1 = j0 + j + 1;
                ja0 = (ja0 < 2064) ? ja0 : 2063;
                ja1 = (ja1 < 2064) ? ja1 : 2063;
                const float4 va = *(const float4*)(Vb0 + (size_t)ja0 * 64);
                const float4 vc = *(const float4*)(Vb0 + (size_t)ja1 * 64);
#pragma unroll
                for (int r = 0; r < 8; ++r) {
                    const float2 a2 = *(const float2*)(ar + r * JP + j);
                    acc[r][0] += a2.x * va.x + a2.y * vc.x;
                    acc[r][1] += a2.x * va.y + a2.y * vc.y;
                    acc[r][2] += a2.x * va.z + a2.y * vc.z;
                    acc[r][3] += a2.x * va.w + a2.y * vc.w;
                }
            }
            __syncthreads();   // PV done before next unit's A2t overwrite
        }
        // ---- flush partials ----
#pragma unroll
        for (int r = 0; r < 8; ++r) {
            float* dst = ho + ((size_t)(b*2048 + i0 + ih*8 + r)) * 1024 + kh*64 + dq*4;
            atomicAdd(dst+0, acc[r][0]);
            atomicAdd(dst+1, acc[r][1]);
            atomicAdd(dst+2, acc[r][2]);
            atomicAdd(dst+3, acc[r][3]);
        }
    }
}

// ---------------------------------------------------------------------------
extern "C" void kernel_launch(void* const* d_in, const int* in_sizes, int n_in,
                              void* d_out, int out_size, void* d_ws, size_t ws_size,
                              hipStream_t stream)
{
    const float* x     = (const float*)d_in[0];
    const float* rope  = (const float*)d_in[1];
    const float* Wq    = (const float*)d_in[2];
    const float* Wk    = (const float*)d_in[3];
    const float* Wv    = (const float*)d_in[4];
    const float* memk  = (const float*)d_in[5];
    const float* memv  = (const float*)d_in[6];
    const float* prew  = (const float*)d_in[7];
    const float* postw = (const float*)d_in[8];
    const float* Wo    = (const float*)d_in[9];
    const float* bo    = (const float*)d_in[10];

    float* out  = (float*)d_out;                      // (2,2048,1024)
    float* pre  = out + (size_t)4194304;              // (2,16,2048,2064)
    float* post = pre + (size_t)135266304;            // (2,16,2048,2064)

    // Scratch parked in the `post` output region (dead before zerofill/fused):
    float* qkv_raw = post;                 // 4096 x 3072
    float* qbuf    = post + 12582912;      // (2,16,2048,64)
    float* kbuf    = post + 16777216;      // (2,16,2064,64)

    // Persistent scratch in d_ws (needs 34.2 MB):
    float* vbuf = (float*)d_ws;            // (2,16,2064,64)
    float* ho   = vbuf + 4227072;          // (2,2048,1024)
    float* mst  = ho + 4194304;            // (2,16,2048)
    float* linv = mst + 65536;             // (2,16,2048)
    if (ws_size < (size_t)8552448 * 4) return;

    // 1) QKV projection
    gemm128<<<dim3(24, 32), 256, 0, stream>>>(x, Wq, Wk, Wv, qkv_raw, nullptr, 3072);
    // 2) rotary + scatter
    rot_scatter<<<dim3(4096, 3), 256, 0, stream>>>(qkv_raw, rope, qbuf, kbuf, vbuf);
    // 3) prepend memory k/v
    memfill<<<dim3(128), 256, 0, stream>>>(memk, memv, kbuf, vbuf);
    // 4) S = scale * q k^T -> pre_softmax_attn (full, unmasked)
    qk_kernel<<<dim3(33, 16, 32), 256, 0, stream>>>(qbuf, kbuf, pre);
    // 5) softmax stats of head-mixed masked logits
    stats_kernel<<<dim3(4096), 256, 0, stream>>>(pre, prew, mst, linv);
    // 6a) zero the masked part of post (overwrites parked scratch - now dead)
    zerofill<<<dim3(65536), 256, 0, stream>>>(post);
    // 6b) ho = 0, then balanced fused softmax+post-mix+PV
    hipMemsetAsync(ho, 0, (size_t)4194304 * 4, stream);
    fused_kernel<<<dim3(64, 4, 2), 512, 0, stream>>>(pre, post, vbuf, prew, postw, mst, linv, ho);
    // 7) out = ho @ Wo^T + bo
    gemm128<<<dim3(8, 32), 256, 0, stream>>>(ho, Wo, Wo, Wo, out, bo, 1024);
}